// Round 13
// baseline (17883.276 us; speedup 1.0000x reference)
//
#include <hip/hip_runtime.h>

// R13: occupancy + selection rework. Keys as u16 (monotone) in LDS, 2-pass
// exact radix threshold, tie-complete collection (cap 48) => superset of the
// proven exact top-32. fp64 re-key + per-column exact top-K unchanged.
// Direct-global phase-1 loads (L1-resident rows, R10 pattern). Fast-math-proof:
// integer exponent tests, integer orderings, finite sentinels.

#define NQ 16384
#define NF 8192
#define D  64
#define TCAP 48
#define RANK 32

typedef unsigned short u16;
typedef unsigned int u32;
typedef unsigned long long u64;

#define IDX_INVALID 0xFFFFFFFFu
#define NANF_BITS   0x7FC00000u
#define FLTMAX_BITS 0x7F7FFFFFu

__device__ __forceinline__ int f32_missing_bits(u32 b) {
    return ((b >> 23) & 0xFFu) == 0xFFu;      // NaN/inf => missing
}

__global__ __launch_bounds__(256, 4) void knn_r13(
        const float* __restrict__ X,
        const float* __restrict__ fit,
        const int* __restrict__ pk,
        float* __restrict__ out) {
    __shared__ __align__(16) unsigned char s_pool[16384]; // s_k16 (16KB) U s_cv (12KB)
    __shared__ u32   s_hist[256];
    __shared__ u32   s_blw[256];
    __shared__ u32   s_tie[256];
    __shared__ float s_xv[D];
    __shared__ u64   s_xmask;
    __shared__ u32   s_ci[TCAP];
    __shared__ double s_kd[TCAP];
    __shared__ u32   s_sel0, s_below0, s_sel1;

    u16*   s_k16 = (u16*)s_pool;
    float* s_cv  = (float*)s_pool;

    const int tid = threadIdx.x;
    const int q = blockIdx.x;

    if (tid < 64) {
        float xf = X[(size_t)q * D + tid];
        int obs = !f32_missing_bits(__float_as_uint(xf));
        s_xv[tid] = obs ? xf : 0.f;
        u64 bal = __ballot(obs != 0);          // tid<64 == wave 0 exactly
        if (tid == 0) s_xmask = bal;
    }
    __syncthreads();

    float xv[D];
#pragma unroll
    for (int j = 0; j < D; ++j) xv[j] = s_xv[j];
    const u64 xm = s_xmask;
    const u32 xmlo = (u32)xm, xmhi = (u32)(xm >> 32);

    // ---- phase 1: fp32 keys (ssd/present); u16-compressed -> LDS ----
    const float4* fitc = (const float4*)fit;
    for (int i = 0; i < 32; ++i) {
        int f = tid + (i << 8);
        float ssd = 0.f; int pres = 0;
#pragma unroll
        for (int m = 0; m < 16; ++m) {
            float4 w = fitc[(size_t)f * 16 + m];
            float ww[4] = { w.x, w.y, w.z, w.w };
#pragma unroll
            for (int u = 0; u < 4; ++u) {
                int j = m * 4 + u;
                int vmiss = f32_missing_bits(__float_as_uint(ww[u]));
                u32 xbit = (j < 32) ? ((xmlo >> j) & 1u) : ((xmhi >> (j - 32)) & 1u);
                int ok = (int)xbit & (vmiss ^ 1);
                float t = ok ? ww[u] : xv[j];  // never selects a NaN
                float dm = xv[j] - t;          // = ok ? x - v : 0
                ssd = fmaf(dm, dm, ssd);
                pres += ok;
            }
        }
        float kk = (pres > 0) ? (ssd / (float)pres) : __uint_as_float(FLTMAX_BITS);
        s_k16[f] = (u16)(__float_as_uint(kk) >> 16);   // monotone compression
    }
    __syncthreads();

    int K = *pk;
    if (K < 1 || K > 64) {                 // robustness if scalar arrived as float
        float kf = __int_as_float(K);
        K = (kf >= 1.f && kf <= 64.f) ? (int)kf : 5;
    }
    if (K > TCAP) K = TCAP;

    // ---- phase 2a: exact rank-32 u16 threshold, 2 byte passes ----
    s_hist[tid] = 0;
    __syncthreads();
    for (int i = 0; i < 32; ++i) {
        u32 k16 = (u32)s_k16[tid + (i << 8)];
        atomicAdd(&s_hist[k16 >> 8], 1u);
    }
    __syncthreads();
    if (tid == 0) {
        u32 run = 0, below = 0, sel = 255;
        for (int b = 0; b < 256; ++b) {
            u32 c = s_hist[b];
            if (run + c >= (u32)RANK) { sel = (u32)b; below = run; break; }
            run += c;
        }
        s_sel0 = sel; s_below0 = below;
    }
    __syncthreads();
    const u32 sel0 = s_sel0;
    const u32 need1 = (u32)RANK - s_below0;
    __syncthreads();
    s_hist[tid] = 0;
    __syncthreads();
    for (int i = 0; i < 32; ++i) {
        u32 k16 = (u32)s_k16[tid + (i << 8)];
        if ((k16 >> 8) == sel0) atomicAdd(&s_hist[k16 & 0xFFu], 1u);
    }
    __syncthreads();
    if (tid == 0) {
        u32 run = 0, sel = 255;
        for (int b = 0; b < 256; ++b) {
            u32 c = s_hist[b];
            if (run + c >= need1) { sel = (u32)b; break; }
            run += c;
        }
        s_sel1 = sel;
    }
    __syncthreads();
    const u32 thr16 = (sel0 << 8) | s_sel1;

    // ---- phase 2a': collection (below + all ties, cap TCAP) ----
    {
        u32 bb = 0, tb = 0;
        for (int i = 0; i < 32; ++i) {
            u32 k16 = (u32)s_k16[tid + (i << 8)];
            bb |= (k16 < thr16)  ? (1u << i) : 0u;
            tb |= (k16 == thr16) ? (1u << i) : 0u;
        }
        s_blw[tid] = bb; s_tie[tid] = tb;
    }
    __syncthreads();
    if (tid == 0) {
        int n = 0;
        for (int t = 0; t < 256 && n < TCAP; ++t) {
            u32 w = s_blw[t];
            while (w && n < TCAP) {
                int i = __ffs(w) - 1; w &= w - 1;
                s_ci[n++] = (u32)(i * 256 + t);   // below-count <= 31 always
            }
        }
        u32 tf[64]; int nt = 0;
        for (int t = 0; t < 256 && nt < 64; ++t) {
            u32 w = s_tie[t];
            while (w && nt < 64) {
                int i = __ffs(w) - 1; w &= w - 1;
                tf[nt++] = (u32)(i * 256 + t);
            }
        }
        int cap = TCAP - n;
        if (nt <= cap) {
            for (int r = 0; r < nt; ++r) s_ci[n++] = tf[r];
        } else {
            for (int j = 0; j < cap; ++j) {       // prefer smallest donor idx
                int bp = -1; u32 bi = IDX_INVALID;
                for (int r = 0; r < nt; ++r)
                    if (tf[r] < bi) { bi = tf[r]; bp = r; }
                tf[bp] = IDX_INVALID;
                s_ci[n++] = bi;
            }
        }
        for (; n < TCAP; ++n) s_ci[n] = IDX_INVALID;
    }
    __syncthreads();

    // ---- phase 2c: stage candidate values (overlays s_k16 — keys dead now) ----
#pragma unroll
    for (int t = 0; t < (TCAP * 64) / 256; ++t) {   // 12 iters
        int idx = tid + t * 256;
        int r = idx >> 6, d2 = idx & 63;
        u32 ci = s_ci[r];
        s_cv[idx] = (ci != IDX_INVALID) ? fit[(size_t)ci * D + d2]
                                        : __uint_as_float(NANF_BITS);
    }

    // ---- phase 2b: exact fp64 re-key of the candidates ----
    if (tid < TCAP) {
        u32 ci = s_ci[tid];
        double kd = 1.0e300;
        if (ci != IDX_INVALID) {
            const float* row = fit + (size_t)ci * D;
            double ss = 0.0; int pr = 0;
#pragma unroll
            for (int j = 0; j < D; ++j) {
                float yf = row[j];
                int vmiss = f32_missing_bits(__float_as_uint(yf));
                u32 xbit = (j < 32) ? ((xmlo >> j) & 1u) : ((xmhi >> (j - 32)) & 1u);
                int ok = (int)xbit & (vmiss ^ 1);
                double dd = ok ? ((double)xv[j] - (double)yf) : 0.0;
                ss = fma(dd, dd, ss);
                pr += ok;
            }
            kd = (pr > 0) ? (ss / (double)pr) : 1.0e300;
        }
        s_kd[tid] = kd;
    }
    __syncthreads();

    // ---- phase 2d: per-column imputation (64 threads) ----
    if (tid < 64) {
        const int d = tid;
        u32 xobs = (d < 32) ? ((xmlo >> d) & 1u) : ((xmhi >> (d - 32)) & 1u);
        float res;
        if (xobs) {
            res = xv[d];
        } else {
            u64 used = 0; float sum = 0.f; int cnt = 0;
            for (int s = 0; s < K; ++s) {
                int best = -1; double bk = 0.0; u32 bi = 0;
                for (int r = 0; r < TCAP; ++r) {
                    if ((used >> r) & 1ull) continue;
                    u32 ci = s_ci[r];
                    if (ci == IDX_INVALID) continue;
                    float v = s_cv[r * 64 + d];
                    if (f32_missing_bits(__float_as_uint(v))) continue;
                    double kd = s_kd[r];
                    if (kd >= 1.0e300) continue;
                    if (best < 0 || kd < bk || (kd == bk && ci < bi)) {
                        best = r; bk = kd; bi = ci;
                    }
                }
                if (best < 0) break;
                used |= 1ull << best;
                sum += s_cv[best * 64 + d];
                cnt++;
            }
            if (cnt > 0) {
                res = sum / (float)cnt;
            } else {
                float cs = 0.f; int cc = 0;        // essentially-never fallback
                for (int f = 0; f < NF; ++f) {
                    float yf = fit[(size_t)f * D + d];
                    if (!f32_missing_bits(__float_as_uint(yf))) { cs += yf; cc++; }
                }
                res = cc > 0 ? cs / (float)cc : 0.f;
            }
            u32 rb = __float_as_uint(res);
            if (((rb >> 23) & 0xFFu) == 0xFFu) res = 0.f;   // integer guard
        }
        out[(size_t)q * D + d] = res;
    }
}

// ---- launch: single dispatch, no workspace ------------------------------------
extern "C" void kernel_launch(void* const* d_in, const int* in_sizes, int n_in,
                              void* d_out, int out_size, void* d_ws, size_t ws_size,
                              hipStream_t stream) {
    const void* pX = d_in[0];
    const void* pF = (n_in > 1) ? d_in[1] : d_in[0];
    const void* pK = (n_in > 2) ? d_in[2] : d_in[0];
    for (int i = 0; i < n_in; ++i) {
        if (in_sizes[i] == NQ * D)      pX = d_in[i];
        else if (in_sizes[i] == NF * D) pF = d_in[i];
        else if (in_sizes[i] == 1)      pK = d_in[i];
    }
    const float* X   = (const float*)pX;
    const float* fit = (const float*)pF;
    const int*   pk  = (const int*)pK;
    float* out = (float*)d_out;

    knn_r13<<<NQ, 256, 0, stream>>>(X, fit, pk, out);
}

// Round 14
// 11064.489 us; speedup vs baseline: 1.6163x; 1.6163x over previous
//
#include <hip/hip_runtime.h>

// R14: spill fix. R13's regression was xv[64] VGPRs + launch_bounds(256,4)
// => scratch spills (38GB fetch / 8GB write of spill traffic). Query row is
// block-uniform -> read from LDS via float4 broadcast instead of registers.
// No min-waves bound. TCAP=64 (candidate values overlay the dead key buffer).
// Selection logic = R13 (2-pass exact u16 radix, bitmask collection, fp64
// re-key, per-column exact top-K). Fast-math-proof throughout.

#define NQ 16384
#define NF 8192
#define D  64
#define TCAP 64
#define RANK 32

typedef unsigned short u16;
typedef unsigned int u32;
typedef unsigned long long u64;

#define IDX_INVALID 0xFFFFFFFFu
#define NANF_BITS   0x7FC00000u
#define FLTMAX_BITS 0x7F7FFFFFu

__device__ __forceinline__ int f32_missing_bits(u32 b) {
    return ((b >> 23) & 0xFFu) == 0xFFu;      // NaN/inf => missing
}

__global__ __launch_bounds__(256) void knn_r14(
        const float* __restrict__ X,
        const float* __restrict__ fit,
        const int* __restrict__ pk,
        float* __restrict__ out) {
    __shared__ __align__(16) unsigned char s_pool[16384]; // s_k16 (16KB) U s_cv (16KB)
    __shared__ u32   s_hist[256];
    __shared__ u32   s_blw[256];
    __shared__ u32   s_tie[256];
    __shared__ __align__(16) float s_xv[D];
    __shared__ u64   s_xmask;
    __shared__ u32   s_ci[TCAP];
    __shared__ double s_kd[TCAP];
    __shared__ u32   s_sel0, s_below0, s_sel1;

    u16*   s_k16 = (u16*)s_pool;
    float* s_cv  = (float*)s_pool;

    const int tid = threadIdx.x;
    const int q = blockIdx.x;

    if (tid < 64) {
        float xf = X[(size_t)q * D + tid];
        int obs = !f32_missing_bits(__float_as_uint(xf));
        s_xv[tid] = obs ? xf : 0.f;
        u64 bal = __ballot(obs != 0);          // tid<64 == wave 0 exactly
        if (tid == 0) s_xmask = bal;
    }
    __syncthreads();

    const u64 xm = s_xmask;
    const u32 xmlo = (u32)xm, xmhi = (u32)(xm >> 32);
    const float4* xv4 = (const float4*)s_xv;   // LDS broadcast reads

    // ---- phase 1: fp32 keys (ssd/present); u16-compressed -> LDS ----
    const float4* fitc = (const float4*)fit;
    for (int i = 0; i < 32; ++i) {
        int f = tid + (i << 8);
        const float4* rp = fitc + (size_t)f * 16;
        float ssd = 0.f; int pres = 0;
#pragma unroll
        for (int m = 0; m < 16; ++m) {
            float4 w = rp[m];
            float4 xc = xv4[m];                // block-uniform broadcast
            u32 mb = (m < 8) ? (xmlo >> ((m & 7) * 4)) : (xmhi >> ((m & 7) * 4));
            float wv[4] = { w.x, w.y, w.z, w.w };
            float xw[4] = { xc.x, xc.y, xc.z, xc.w };
#pragma unroll
            for (int u = 0; u < 4; ++u) {
                int ok = (int)((mb >> u) & 1u)
                       & (f32_missing_bits(__float_as_uint(wv[u])) ^ 1);
                float t = ok ? wv[u] : xw[u];  // never selects a NaN
                float dm = xw[u] - t;          // = ok ? x - v : 0
                ssd = fmaf(dm, dm, ssd);
                pres += ok;
            }
        }
        float kk = (pres > 0) ? (ssd / (float)pres) : __uint_as_float(FLTMAX_BITS);
        s_k16[f] = (u16)(__float_as_uint(kk) >> 16);   // monotone compression
    }
    __syncthreads();

    int K = *pk;
    if (K < 1 || K > 64) {                 // robustness if scalar arrived as float
        float kf = __int_as_float(K);
        K = (kf >= 1.f && kf <= 64.f) ? (int)kf : 5;
    }
    if (K > TCAP) K = TCAP;

    // ---- phase 2a: exact rank-32 u16 threshold, 2 byte passes ----
    s_hist[tid] = 0;
    __syncthreads();
    for (int i = 0; i < 32; ++i) {
        u32 k16 = (u32)s_k16[tid + (i << 8)];
        atomicAdd(&s_hist[k16 >> 8], 1u);
    }
    __syncthreads();
    if (tid == 0) {
        u32 run = 0, below = 0, sel = 255;
        for (int b = 0; b < 256; ++b) {
            u32 c = s_hist[b];
            if (run + c >= (u32)RANK) { sel = (u32)b; below = run; break; }
            run += c;
        }
        s_sel0 = sel; s_below0 = below;
    }
    __syncthreads();
    const u32 sel0 = s_sel0;
    const u32 need1 = (u32)RANK - s_below0;
    __syncthreads();
    s_hist[tid] = 0;
    __syncthreads();
    for (int i = 0; i < 32; ++i) {
        u32 k16 = (u32)s_k16[tid + (i << 8)];
        if ((k16 >> 8) == sel0) atomicAdd(&s_hist[k16 & 0xFFu], 1u);
    }
    __syncthreads();
    if (tid == 0) {
        u32 run = 0, sel = 255;
        for (int b = 0; b < 256; ++b) {
            u32 c = s_hist[b];
            if (run + c >= need1) { sel = (u32)b; break; }
            run += c;
        }
        s_sel1 = sel;
    }
    __syncthreads();
    const u32 thr16 = (sel0 << 8) | s_sel1;

    // ---- phase 2a': collection (below + ties, cap TCAP) ----
    {
        u32 bb = 0, tb = 0;
        for (int i = 0; i < 32; ++i) {
            u32 k16 = (u32)s_k16[tid + (i << 8)];
            bb |= (k16 < thr16)  ? (1u << i) : 0u;
            tb |= (k16 == thr16) ? (1u << i) : 0u;
        }
        s_blw[tid] = bb; s_tie[tid] = tb;
    }
    __syncthreads();
    if (tid == 0) {
        int n = 0;
        for (int t = 0; t < 256 && n < TCAP; ++t) {
            u32 w = s_blw[t];
            while (w && n < TCAP) {
                int i = __ffs(w) - 1; w &= w - 1;
                s_ci[n++] = (u32)(i * 256 + t);   // below-count <= 31 always
            }
        }
        u32 tf[TCAP]; int nt = 0;
        for (int t = 0; t < 256 && nt < TCAP; ++t) {
            u32 w = s_tie[t];
            while (w && nt < TCAP) {
                int i = __ffs(w) - 1; w &= w - 1;
                tf[nt++] = (u32)(i * 256 + t);
            }
        }
        int cap = TCAP - n;
        if (nt <= cap) {
            for (int r = 0; r < nt; ++r) s_ci[n++] = tf[r];
        } else {
            for (int j = 0; j < cap; ++j) {       // prefer smallest donor idx
                int bp = -1; u32 bi = IDX_INVALID;
                for (int r = 0; r < nt; ++r)
                    if (tf[r] < bi) { bi = tf[r]; bp = r; }
                tf[bp] = IDX_INVALID;
                s_ci[n++] = bi;
            }
        }
        for (; n < TCAP; ++n) s_ci[n] = IDX_INVALID;
    }
    __syncthreads();

    // ---- phase 2c: stage candidate values (overlays s_k16 — keys dead now) ----
#pragma unroll
    for (int t = 0; t < (TCAP * 64) / 256; ++t) {   // 16 iters
        int idx = tid + t * 256;
        int r = idx >> 6, d2 = idx & 63;
        u32 ci = s_ci[r];
        s_cv[idx] = (ci != IDX_INVALID) ? fit[(size_t)ci * D + d2]
                                        : __uint_as_float(NANF_BITS);
    }

    // ---- phase 2b: exact fp64 re-key of the candidates ----
    if (tid < TCAP) {
        u32 ci = s_ci[tid];
        double kd = 1.0e300;
        if (ci != IDX_INVALID) {
            const float* row = fit + (size_t)ci * D;
            double ss = 0.0; int pr = 0;
            for (int j = 0; j < D; ++j) {
                float yf = row[j];
                int vmiss = f32_missing_bits(__float_as_uint(yf));
                u32 xbit = (j < 32) ? ((xmlo >> j) & 1u) : ((xmhi >> (j - 32)) & 1u);
                int ok = (int)xbit & (vmiss ^ 1);
                double dd = ok ? ((double)s_xv[j] - (double)yf) : 0.0;
                ss = fma(dd, dd, ss);
                pr += ok;
            }
            kd = (pr > 0) ? (ss / (double)pr) : 1.0e300;
        }
        s_kd[tid] = kd;
    }
    __syncthreads();

    // ---- phase 2d: per-column imputation (64 threads) ----
    if (tid < 64) {
        const int d = tid;
        u32 xobs = (d < 32) ? ((xmlo >> d) & 1u) : ((xmhi >> (d - 32)) & 1u);
        float res;
        if (xobs) {
            res = s_xv[d];
        } else {
            u64 used = 0; float sum = 0.f; int cnt = 0;
            for (int s = 0; s < K; ++s) {
                int best = -1; double bk = 0.0; u32 bi = 0;
                for (int r = 0; r < TCAP; ++r) {
                    if ((used >> r) & 1ull) continue;
                    u32 ci = s_ci[r];
                    if (ci == IDX_INVALID) continue;
                    float v = s_cv[r * 64 + d];
                    if (f32_missing_bits(__float_as_uint(v))) continue;
                    double kd = s_kd[r];
                    if (kd >= 1.0e300) continue;
                    if (best < 0 || kd < bk || (kd == bk && ci < bi)) {
                        best = r; bk = kd; bi = ci;
                    }
                }
                if (best < 0) break;
                used |= 1ull << best;
                sum += s_cv[best * 64 + d];
                cnt++;
            }
            if (cnt > 0) {
                res = sum / (float)cnt;
            } else {
                float cs = 0.f; int cc = 0;        // essentially-never fallback
                for (int f = 0; f < NF; ++f) {
                    float yf = fit[(size_t)f * D + d];
                    if (!f32_missing_bits(__float_as_uint(yf))) { cs += yf; cc++; }
                }
                res = cc > 0 ? cs / (float)cc : 0.f;
            }
            u32 rb = __float_as_uint(res);
            if (((rb >> 23) & 0xFFu) == 0xFFu) res = 0.f;   // integer guard
        }
        out[(size_t)q * D + d] = res;
    }
}

// ---- launch: single dispatch, no workspace ------------------------------------
extern "C" void kernel_launch(void* const* d_in, const int* in_sizes, int n_in,
                              void* d_out, int out_size, void* d_ws, size_t ws_size,
                              hipStream_t stream) {
    const void* pX = d_in[0];
    const void* pF = (n_in > 1) ? d_in[1] : d_in[0];
    const void* pK = (n_in > 2) ? d_in[2] : d_in[0];
    for (int i = 0; i < n_in; ++i) {
        if (in_sizes[i] == NQ * D)      pX = d_in[i];
        else if (in_sizes[i] == NF * D) pF = d_in[i];
        else if (in_sizes[i] == 1)      pK = d_in[i];
    }
    const float* X   = (const float*)pX;
    const float* fit = (const float*)pF;
    const int*   pk  = (const int*)pK;
    float* out = (float*)d_out;

    knn_r14<<<NQ, 256, 0, stream>>>(X, fit, pk, out);
}

// Round 15
// 9786.193 us; speedup vs baseline: 1.8274x; 1.1306x over previous
//
#include <hip/hip_runtime.h>

// R15: coalescing fix for phase 1. R14's ~85% stall = uncoalesced row-major
// loads (64 distinct lines per wave inst). Relayout fit into workspace as
// feature-group-major float4 (fit4[g][f] = features 4g..4g+3 of donor f):
// phase-1 loads become lane-consecutive 16B => 16 line-txns/inst (4x fewer).
// Key arithmetic bit-identical to R14. ws_size-guarded fallback = R14 path.
// Selection: 2-pass exact u16 radix + bitmask collection + fp64 re-key +
// per-column exact top-K (proven). Fast-math-proof throughout.

#define NQ 16384
#define NF 8192
#define D  64
#define TCAP 64
#define RANK 32

typedef unsigned short u16;
typedef unsigned int u32;
typedef unsigned long long u64;

#define IDX_INVALID 0xFFFFFFFFu
#define NANF_BITS   0x7FC00000u
#define FLTMAX_BITS 0x7F7FFFFFu

__device__ __forceinline__ int f32_missing_bits(u32 b) {
    return ((b >> 23) & 0xFFu) == 0xFFu;      // NaN/inf => missing
}

// ---- prep: fit (row-major [NF,64]) -> fit4 (group-major [16][NF] float4) ----
__global__ __launch_bounds__(256) void prep_fit4(const float* __restrict__ fit,
                                                 float4* __restrict__ fit4) {
    int idx = blockIdx.x * 256 + threadIdx.x;     // 0 .. NF*16-1
    int g = idx / NF;                              // feature group 0..15
    int f = idx - g * NF;                          // donor
    const float4* src = (const float4*)(fit + (size_t)f * D);
    fit4[(size_t)g * NF + f] = src[g];             // scattered read, coalesced write
}

__global__ __launch_bounds__(256) void knn_r15(
        const float* __restrict__ X,
        const float* __restrict__ fit,
        const float4* __restrict__ fit4,          // may be null -> fallback path
        const int* __restrict__ pk,
        float* __restrict__ out) {
    __shared__ __align__(16) unsigned char s_pool[16384]; // s_k16 (16KB) U s_cv (16KB)
    __shared__ u32   s_hist[256];
    __shared__ u32   s_blw[256];
    __shared__ u32   s_tie[256];
    __shared__ __align__(16) float s_xv[D];
    __shared__ u64   s_xmask;
    __shared__ u32   s_ci[TCAP];
    __shared__ double s_kd[TCAP];
    __shared__ u32   s_sel0, s_below0, s_sel1;

    u16*   s_k16 = (u16*)s_pool;
    float* s_cv  = (float*)s_pool;

    const int tid = threadIdx.x;
    const int q = blockIdx.x;

    if (tid < 64) {
        float xf = X[(size_t)q * D + tid];
        int obs = !f32_missing_bits(__float_as_uint(xf));
        s_xv[tid] = obs ? xf : 0.f;
        u64 bal = __ballot(obs != 0);          // tid<64 == wave 0 exactly
        if (tid == 0) s_xmask = bal;
    }
    __syncthreads();

    const u64 xm = s_xmask;
    const u32 xmlo = (u32)xm, xmhi = (u32)(xm >> 32);
    const float4* xv4 = (const float4*)s_xv;   // LDS broadcast reads

    // ---- phase 1: fp32 keys (ssd/present); u16-compressed -> LDS ----
    if (fit4 != nullptr) {
        // coalesced group-major path: lane-consecutive f, 16B/lane
        for (int i = 0; i < 32; ++i) {
            int f = tid + (i << 8);
            float ssd = 0.f; int pres = 0;
#pragma unroll
            for (int m = 0; m < 16; ++m) {
                float4 w = fit4[(size_t)m * NF + f];
                float4 xc = xv4[m];
                u32 mb = (m < 8) ? (xmlo >> ((m & 7) * 4)) : (xmhi >> ((m & 7) * 4));
                float wv[4] = { w.x, w.y, w.z, w.w };
                float xw[4] = { xc.x, xc.y, xc.z, xc.w };
#pragma unroll
                for (int u = 0; u < 4; ++u) {
                    int ok = (int)((mb >> u) & 1u)
                           & (f32_missing_bits(__float_as_uint(wv[u])) ^ 1);
                    float t = ok ? wv[u] : xw[u];
                    float dm = xw[u] - t;          // = ok ? x - v : 0
                    ssd = fmaf(dm, dm, ssd);
                    pres += ok;
                }
            }
            float kk = (pres > 0) ? (ssd / (float)pres) : __uint_as_float(FLTMAX_BITS);
            s_k16[f] = (u16)(__float_as_uint(kk) >> 16);
        }
    } else {
        // fallback: R14 row-major path
        const float4* fitc = (const float4*)fit;
        for (int i = 0; i < 32; ++i) {
            int f = tid + (i << 8);
            const float4* rp = fitc + (size_t)f * 16;
            float ssd = 0.f; int pres = 0;
#pragma unroll
            for (int m = 0; m < 16; ++m) {
                float4 w = rp[m];
                float4 xc = xv4[m];
                u32 mb = (m < 8) ? (xmlo >> ((m & 7) * 4)) : (xmhi >> ((m & 7) * 4));
                float wv[4] = { w.x, w.y, w.z, w.w };
                float xw[4] = { xc.x, xc.y, xc.z, xc.w };
#pragma unroll
                for (int u = 0; u < 4; ++u) {
                    int ok = (int)((mb >> u) & 1u)
                           & (f32_missing_bits(__float_as_uint(wv[u])) ^ 1);
                    float t = ok ? wv[u] : xw[u];
                    float dm = xw[u] - t;
                    ssd = fmaf(dm, dm, ssd);
                    pres += ok;
                }
            }
            float kk = (pres > 0) ? (ssd / (float)pres) : __uint_as_float(FLTMAX_BITS);
            s_k16[f] = (u16)(__float_as_uint(kk) >> 16);
        }
    }
    __syncthreads();

    int K = *pk;
    if (K < 1 || K > 64) {                 // robustness if scalar arrived as float
        float kf = __int_as_float(K);
        K = (kf >= 1.f && kf <= 64.f) ? (int)kf : 5;
    }
    if (K > TCAP) K = TCAP;

    // ---- phase 2a: exact rank-32 u16 threshold, 2 byte passes ----
    s_hist[tid] = 0;
    __syncthreads();
    for (int i = 0; i < 32; ++i) {
        u32 k16 = (u32)s_k16[tid + (i << 8)];
        atomicAdd(&s_hist[k16 >> 8], 1u);
    }
    __syncthreads();
    if (tid == 0) {
        u32 run = 0, below = 0, sel = 255;
        for (int b = 0; b < 256; ++b) {
            u32 c = s_hist[b];
            if (run + c >= (u32)RANK) { sel = (u32)b; below = run; break; }
            run += c;
        }
        s_sel0 = sel; s_below0 = below;
    }
    __syncthreads();
    const u32 sel0 = s_sel0;
    const u32 need1 = (u32)RANK - s_below0;
    __syncthreads();
    s_hist[tid] = 0;
    __syncthreads();
    for (int i = 0; i < 32; ++i) {
        u32 k16 = (u32)s_k16[tid + (i << 8)];
        if ((k16 >> 8) == sel0) atomicAdd(&s_hist[k16 & 0xFFu], 1u);
    }
    __syncthreads();
    if (tid == 0) {
        u32 run = 0, sel = 255;
        for (int b = 0; b < 256; ++b) {
            u32 c = s_hist[b];
            if (run + c >= need1) { sel = (u32)b; break; }
            run += c;
        }
        s_sel1 = sel;
    }
    __syncthreads();
    const u32 thr16 = (sel0 << 8) | s_sel1;

    // ---- phase 2a': collection (below + ties, cap TCAP) ----
    {
        u32 bb = 0, tb = 0;
        for (int i = 0; i < 32; ++i) {
            u32 k16 = (u32)s_k16[tid + (i << 8)];
            bb |= (k16 < thr16)  ? (1u << i) : 0u;
            tb |= (k16 == thr16) ? (1u << i) : 0u;
        }
        s_blw[tid] = bb; s_tie[tid] = tb;
    }
    __syncthreads();
    if (tid == 0) {
        int n = 0;
        for (int t = 0; t < 256 && n < TCAP; ++t) {
            u32 w = s_blw[t];
            while (w && n < TCAP) {
                int i = __ffs(w) - 1; w &= w - 1;
                s_ci[n++] = (u32)(i * 256 + t);   // below-count <= 31 always
            }
        }
        u32 tf[TCAP]; int nt = 0;
        for (int t = 0; t < 256 && nt < TCAP; ++t) {
            u32 w = s_tie[t];
            while (w && nt < TCAP) {
                int i = __ffs(w) - 1; w &= w - 1;
                tf[nt++] = (u32)(i * 256 + t);
            }
        }
        int cap = TCAP - n;
        if (nt <= cap) {
            for (int r = 0; r < nt; ++r) s_ci[n++] = tf[r];
        } else {
            for (int j = 0; j < cap; ++j) {       // prefer smallest donor idx
                int bp = -1; u32 bi = IDX_INVALID;
                for (int r = 0; r < nt; ++r)
                    if (tf[r] < bi) { bi = tf[r]; bp = r; }
                tf[bp] = IDX_INVALID;
                s_ci[n++] = bi;
            }
        }
        for (; n < TCAP; ++n) s_ci[n] = IDX_INVALID;
    }
    __syncthreads();

    // ---- phase 2c: stage candidate values (overlays s_k16 — keys dead now) ----
#pragma unroll
    for (int t = 0; t < (TCAP * 64) / 256; ++t) {   // 16 iters
        int idx = tid + t * 256;
        int r = idx >> 6, d2 = idx & 63;
        u32 ci = s_ci[r];
        s_cv[idx] = (ci != IDX_INVALID) ? fit[(size_t)ci * D + d2]
                                        : __uint_as_float(NANF_BITS);
    }

    // ---- phase 2b: exact fp64 re-key of the candidates ----
    if (tid < TCAP) {
        u32 ci = s_ci[tid];
        double kd = 1.0e300;
        if (ci != IDX_INVALID) {
            const float* row = fit + (size_t)ci * D;
            double ss = 0.0; int pr = 0;
            for (int j = 0; j < D; ++j) {
                float yf = row[j];
                int vmiss = f32_missing_bits(__float_as_uint(yf));
                u32 xbit = (j < 32) ? ((xmlo >> j) & 1u) : ((xmhi >> (j - 32)) & 1u);
                int ok = (int)xbit & (vmiss ^ 1);
                double dd = ok ? ((double)s_xv[j] - (double)yf) : 0.0;
                ss = fma(dd, dd, ss);
                pr += ok;
            }
            kd = (pr > 0) ? (ss / (double)pr) : 1.0e300;
        }
        s_kd[tid] = kd;
    }
    __syncthreads();

    // ---- phase 2d: per-column imputation (64 threads) ----
    if (tid < 64) {
        const int d = tid;
        u32 xobs = (d < 32) ? ((xmlo >> d) & 1u) : ((xmhi >> (d - 32)) & 1u);
        float res;
        if (xobs) {
            res = s_xv[d];
        } else {
            u64 used = 0; float sum = 0.f; int cnt = 0;
            for (int s = 0; s < K; ++s) {
                int best = -1; double bk = 0.0; u32 bi = 0;
                for (int r = 0; r < TCAP; ++r) {
                    if ((used >> r) & 1ull) continue;
                    u32 ci = s_ci[r];
                    if (ci == IDX_INVALID) continue;
                    float v = s_cv[r * 64 + d];
                    if (f32_missing_bits(__float_as_uint(v))) continue;
                    double kd = s_kd[r];
                    if (kd >= 1.0e300) continue;
                    if (best < 0 || kd < bk || (kd == bk && ci < bi)) {
                        best = r; bk = kd; bi = ci;
                    }
                }
                if (best < 0) break;
                used |= 1ull << best;
                sum += s_cv[best * 64 + d];
                cnt++;
            }
            if (cnt > 0) {
                res = sum / (float)cnt;
            } else {
                float cs = 0.f; int cc = 0;        // essentially-never fallback
                for (int f = 0; f < NF; ++f) {
                    float yf = fit[(size_t)f * D + d];
                    if (!f32_missing_bits(__float_as_uint(yf))) { cs += yf; cc++; }
                }
                res = cc > 0 ? cs / (float)cc : 0.f;
            }
            u32 rb = __float_as_uint(res);
            if (((rb >> 23) & 0xFFu) == 0xFFu) res = 0.f;   // integer guard
        }
        out[(size_t)q * D + d] = res;
    }
}

// ---- launch ------------------------------------------------------------------
extern "C" void kernel_launch(void* const* d_in, const int* in_sizes, int n_in,
                              void* d_out, int out_size, void* d_ws, size_t ws_size,
                              hipStream_t stream) {
    const void* pX = d_in[0];
    const void* pF = (n_in > 1) ? d_in[1] : d_in[0];
    const void* pK = (n_in > 2) ? d_in[2] : d_in[0];
    for (int i = 0; i < n_in; ++i) {
        if (in_sizes[i] == NQ * D)      pX = d_in[i];
        else if (in_sizes[i] == NF * D) pF = d_in[i];
        else if (in_sizes[i] == 1)      pK = d_in[i];
    }
    const float* X   = (const float*)pX;
    const float* fit = (const float*)pF;
    const int*   pk  = (const int*)pK;
    float* out = (float*)d_out;

    const size_t need = (size_t)NF * D * sizeof(float);   // 2 MB
    if (ws_size >= need) {
        float4* fit4 = (float4*)d_ws;
        prep_fit4<<<(NF * 16) / 256, 256, 0, stream>>>(fit, fit4);
        knn_r15<<<NQ, 256, 0, stream>>>(X, fit, fit4, pk, out);
    } else {
        knn_r15<<<NQ, 256, 0, stream>>>(X, fit, nullptr, pk, out);
    }
}